// Round 8
// baseline (315.271 us; speedup 1.0000x reference)
//
#include <hip/hip_runtime.h>
#include <math.h>

#define NN 4096
#define DD 512
#define FF 512
#define CAP 256
#define SCALE 0.08838834764831845f

typedef unsigned short u16;
typedef __attribute__((ext_vector_type(8))) short short8;
typedef __attribute__((ext_vector_type(8))) unsigned short ushort8;
typedef __attribute__((ext_vector_type(4))) unsigned short ushort4v;
typedef __attribute__((ext_vector_type(4))) float floatx4;

__device__ __forceinline__ float bf2f(u16 u) {
    union { unsigned int i; float f; } x; x.i = ((unsigned int)u) << 16; return x.f;
}
__device__ __forceinline__ u16 f2bf(float f) {
    union { float f; unsigned int i; } x; x.f = f;
    unsigned int r = (x.i + 0x7FFFu + ((x.i >> 16) & 1u)) >> 16;
    return (u16)r;
}
__device__ __forceinline__ void gld_lds16(const void* g, void* l) {
    __builtin_amdgcn_global_load_lds((const __attribute__((address_space(1))) void*)g,
                                     (__attribute__((address_space(3))) void*)l, 16, 0, 0);
}

// ---------------------------------------------------------------- mask -> idx (R3-proven)
__global__ void build_idx_kernel(const int* __restrict__ mask,
                                 int* __restrict__ idx, int* __restrict__ cnt) {
    int row = blockIdx.x;
    __shared__ int c;
    if (threadIdx.x == 0) c = 0;
    __syncthreads();
    const int4* mrow = (const int4*)(mask + (size_t)row * NN);
    for (int j4 = threadIdx.x; j4 < NN / 4; j4 += blockDim.x) {
        int4 m4 = mrow[j4];
        int base = j4 * 4;
        if (m4.x == 0) idx[row * CAP + atomicAdd(&c, 1)] = base;
        if (m4.y == 0) idx[row * CAP + atomicAdd(&c, 1)] = base + 1;
        if (m4.z == 0) idx[row * CAP + atomicAdd(&c, 1)] = base + 2;
        if (m4.w == 0) idx[row * CAP + atomicAdd(&c, 1)] = base + 3;
    }
    __syncthreads();
    if (threadIdx.x == 0) cnt[row] = (c < CAP) ? c : CAP;
}

// ---------------------------------------------------------------- weights fp32 -> bf16 (+ bias concat)
struct W6 {
    const float* w[6];
    const float* bq; const float* bk; const float* bv;
};
__global__ void cast_weights(W6 wp, u16* __restrict__ dst, float* __restrict__ bcat) {
    int region = blockIdx.x >> 4;
    int layer = region / 6, mat = region - layer * 6;
    const float* src = wp.w[mat] + (size_t)layer * (DD * DD);
    u16* d = dst + (size_t)region * (DD * DD);
    int off = (blockIdx.x & 15) * 16384 + threadIdx.x * 4;
#pragma unroll
    for (int i = 0; i < 16; i++) {
        int e = off + i * 1024;
        float4 f = *(const float4*)&src[e];
        ushort4v u;
        u.x = f2bf(f.x); u.y = f2bf(f.y); u.z = f2bf(f.z); u.w = f2bf(f.w);
        *(ushort4v*)&d[e] = u;
    }
    if (blockIdx.x < 2) {   // bias concat for layer = blockIdx.x
        int l = blockIdx.x;
        for (int it = 0; it < 6; it++) {
            int j = it * 256 + threadIdx.x;          // 0..1535
            int m = j >> 9, col = j & 511;
            const float* bp = (m == 0) ? wp.bq : (m == 1) ? wp.bk : wp.bv;
            bcat[l * 1536 + j] = bp[l * DD + col];
        }
    }
}

// ---------------------------------------------------------------- layernorm (fp32 in, bf16 out)
__global__ void ln_kernel(const float* __restrict__ x, const float* __restrict__ g,
                          const float* __restrict__ b, u16* __restrict__ out) {
    int wave = threadIdx.x >> 6, lane = threadIdx.x & 63;
    int row = blockIdx.x * 4 + wave;
    const float* xr = x + (size_t)row * DD;
    float4 p0 = *(const float4*)&xr[lane * 8];
    float4 p1 = *(const float4*)&xr[lane * 8 + 4];
    float v[8] = {p0.x, p0.y, p0.z, p0.w, p1.x, p1.y, p1.z, p1.w};
    float s = 0.f;
#pragma unroll
    for (int i = 0; i < 8; i++) s += v[i];
#pragma unroll
    for (int off = 32; off; off >>= 1) s += __shfl_xor(s, off);
    float mu = s * (1.0f / DD);
    float vs = 0.f;
#pragma unroll
    for (int i = 0; i < 8; i++) { float d = v[i] - mu; vs += d * d; }
#pragma unroll
    for (int off = 32; off; off >>= 1) vs += __shfl_xor(vs, off);
    float r = rsqrtf(vs * (1.0f / DD) + 1e-5f);
    float4 g0 = *(const float4*)&g[lane * 8];
    float4 g1 = *(const float4*)&g[lane * 8 + 4];
    float4 b0 = *(const float4*)&b[lane * 8];
    float4 b1 = *(const float4*)&b[lane * 8 + 4];
    float ge[8] = {g0.x, g0.y, g0.z, g0.w, g1.x, g1.y, g1.z, g1.w};
    float be[8] = {b0.x, b0.y, b0.z, b0.w, b1.x, b1.y, b1.z, b1.w};
    ushort8 ov;
#pragma unroll
    for (int i = 0; i < 8; i++) ov[i] = f2bf((v[i] - mu) * r * ge[i] + be[i]);
    *(ushort8*)&out[(size_t)row * DD + lane * 8] = ov;
}

// LDS chunk swizzle: LDS(row, pos) holds global chunk ((pos + (row>>1)) & 3).
// Reader of global chunk g at row R uses pos = (g - (R>>1)) & 3.
// Banks: (16R + 4p) mod 32 -> exactly 2 lanes/bank (free) vs 8-way unswizzled.

// ---------------------------------------------------------------- 64x64 GEMM (swizzled LDS)
// MODE 0: -> bf16; 1: gelu -> bf16; 2: resOut = resIn + val (fp32)
template <int MODE>
__launch_bounds__(256)
__global__ void gemm_bf16(const u16* __restrict__ A, const u16* __restrict__ B,
                          const float* __restrict__ bias, const float* __restrict__ resIn,
                          float* __restrict__ resOut, u16* __restrict__ outB,
                          int M, int Nout, int K) {
    __shared__ u16 As[64 * 32];
    __shared__ u16 Bs[64 * 32];
    const int m0 = blockIdx.y * 64, n0 = blockIdx.x * 64;
    const int t = threadIdx.x;
    const int wave = t >> 6, lane = t & 63;
    const int wm = (wave & 1) * 32, wn = (wave >> 1) * 32;
    const int srow = t >> 2;
    const int scol = (((t & 3) + (t >> 3)) & 3) * 8;        // swizzled source chunk
    const int fr = lane & 15, g = lane >> 4;
    const int fp = ((g - (fr >> 1)) & 3) * 8;               // swizzled frag offset

    floatx4 acc[2][2] = {};
    const u16* ag = A + (size_t)(m0 + srow) * K + scol;
    const u16* bg = B + (size_t)(n0 + srow) * K + scol;
    u16* as = As + t * 8;
    u16* bs = Bs + t * 8;

    for (int k0 = 0; k0 < K; k0 += 32) {
        __syncthreads();
        gld_lds16(ag + k0, as);
        gld_lds16(bg + k0, bs);
        __syncthreads();
        short8 af[2], bf[2];
#pragma unroll
        for (int i = 0; i < 2; i++) af[i] = *(const short8*)&As[(wm + 16 * i + fr) * 32 + fp];
#pragma unroll
        for (int j = 0; j < 2; j++) bf[j] = *(const short8*)&Bs[(wn + 16 * j + fr) * 32 + fp];
#pragma unroll
        for (int i = 0; i < 2; i++)
#pragma unroll
            for (int j = 0; j < 2; j++)
                acc[i][j] = __builtin_amdgcn_mfma_f32_16x16x32_bf16(af[i], bf[j], acc[i][j], 0, 0, 0);
    }

    const int er = (lane >> 4) * 4, ec = lane & 15;
#pragma unroll
    for (int i = 0; i < 2; i++) {
#pragma unroll
        for (int j = 0; j < 2; j++) {
            int col = n0 + wn + 16 * j + ec;
            float bsv = bias[col];
#pragma unroll
            for (int r = 0; r < 4; r++) {
                int row = m0 + wm + 16 * i + er + r;
                float val = acc[i][j][r] + bsv;
                if (MODE == 1) val = 0.5f * val * (1.0f + erff(val * 0.70710678118654752f));
                if (MODE == 2) {
                    resOut[(size_t)row * Nout + col] = resIn[(size_t)row * Nout + col] + val;
                } else {
                    outB[(size_t)row * Nout + col] = f2bf(val);
                }
            }
        }
    }
}

// ---------------------------------------------------------------- 128x64 QKV GEMM (swizzled LDS)
__launch_bounds__(256)
__global__ void gemm_qkv(const u16* __restrict__ A, const u16* __restrict__ B,
                         const float* __restrict__ bias, u16* __restrict__ outB) {
    __shared__ u16 As[128 * 32];
    __shared__ u16 Bs[64 * 32];
    const int m0 = blockIdx.y * 128, n0 = blockIdx.x * 64;
    const int t = threadIdx.x;
    const int wave = t >> 6, lane = t & 63;
    const int wm = (wave & 1) * 64, wn = (wave >> 1) * 32;
    const int srow = t >> 2;
    const int scol = (((t & 3) + (t >> 3)) & 3) * 8;
    const int fr = lane & 15, g = lane >> 4;
    const int fp = ((g - (fr >> 1)) & 3) * 8;

    floatx4 acc[4][2] = {};
    const u16* ag0 = A + (size_t)(m0 + srow) * DD + scol;
    const u16* ag1 = ag0 + (size_t)64 * DD;
    const u16* bg = B + (size_t)(n0 + srow) * DD + scol;
    u16* as0 = As + t * 8;
    u16* as1 = as0 + 64 * 32;
    u16* bs = Bs + t * 8;

    for (int k0 = 0; k0 < DD; k0 += 32) {
        __syncthreads();
        gld_lds16(ag0 + k0, as0);
        gld_lds16(ag1 + k0, as1);
        gld_lds16(bg + k0, bs);
        __syncthreads();
        short8 af[4], bf[2];
#pragma unroll
        for (int i = 0; i < 4; i++) af[i] = *(const short8*)&As[(wm + 16 * i + fr) * 32 + fp];
#pragma unroll
        for (int j = 0; j < 2; j++) bf[j] = *(const short8*)&Bs[(wn + 16 * j + fr) * 32 + fp];
#pragma unroll
        for (int i = 0; i < 4; i++)
#pragma unroll
            for (int j = 0; j < 2; j++)
                acc[i][j] = __builtin_amdgcn_mfma_f32_16x16x32_bf16(af[i], bf[j], acc[i][j], 0, 0, 0);
    }

    const int er = (lane >> 4) * 4, ec = lane & 15;
#pragma unroll
    for (int j = 0; j < 2; j++) {
        int col = n0 + wn + 16 * j + ec;
        float bsv = bias[col];
#pragma unroll
        for (int i = 0; i < 4; i++) {
#pragma unroll
            for (int r = 0; r < 4; r++) {
                int row = m0 + wm + 16 * i + er + r;
                outB[(size_t)row * 1536 + col] = f2bf(acc[i][j][r] + bsv);
            }
        }
    }
}

// ---------------------------------------------------------------- sparse attention
// 2 waves/query, 4 queries/block; idx in LDS; batch-4 K/V prefetch
__global__ void sparse_attn(const u16* __restrict__ qkv, const int* __restrict__ idx,
                            const int* __restrict__ cnt, u16* __restrict__ o) {
    int t = threadIdx.x;
    int wave = t >> 6, lane = t & 63;
    int qslot = wave >> 1, half = wave & 1;
    int qi = blockIdx.x * 4 + qslot;
    __shared__ float obuf[4][64][8];
    __shared__ float sbuf[4][64];
    __shared__ int sidx[4][CAP];

    int c = cnt[qi];
    const int* ir = idx + qi * CAP;
    for (int j = t & 127; j < c; j += 128) sidx[qslot][j] = ir[j];

    ushort8 qv = *(const ushort8*)(qkv + (size_t)qi * 1536 + lane * 8);
    float qf[8];
#pragma unroll
    for (int e = 0; e < 8; e++) qf[e] = bf2f(qv[e]);
    __syncthreads();

    float sum = 0.f, oa[8] = {};
    for (int jb = half; jb < c; jb += 8) {
        ushort8 kv[4], vv[4];
#pragma unroll
        for (int u = 0; u < 4; u++) {
            int j = jb + 2 * u;
            int kj = (j < c) ? sidx[qslot][j] : qi;
            const u16* kb = qkv + (size_t)kj * 1536;
            kv[u] = *(const ushort8*)(kb + 512 + lane * 8);
            vv[u] = *(const ushort8*)(kb + 1024 + lane * 8);
        }
#pragma unroll
        for (int u = 0; u < 4; u++) {
            int j = jb + 2 * u;
            if (j >= c) break;
            float d = 0.f;
#pragma unroll
            for (int e = 0; e < 8; e++) d += qf[e] * bf2f(kv[u][e]);
            d += __shfl_xor(d, 1);
            d += __shfl_xor(d, 2);
            d += __shfl_xor(d, 4);
            d += __shfl_xor(d, 8);
            float p = __expf(d * SCALE);
            sum += p;
#pragma unroll
            for (int e = 0; e < 8; e++) oa[e] += p * bf2f(vv[u][e]);
        }
    }

    if (half == 1) {
#pragma unroll
        for (int e = 0; e < 8; e++) obuf[qslot][lane][e] = oa[e];
        sbuf[qslot][lane] = sum;
    }
    __syncthreads();
    if (half == 0) {
        sum += sbuf[qslot][lane];
        float inv = 1.0f / sum;
        ushort8 ov;
#pragma unroll
        for (int e = 0; e < 8; e++) ov[e] = f2bf((oa[e] + obuf[qslot][lane][e]) * inv);
        *(ushort8*)(o + (size_t)qi * 512 + lane * 8) = ov;
    }
}

// ---------------------------------------------------------------- launch
extern "C" void kernel_launch(void* const* d_in, const int* in_sizes, int n_in,
                              void* d_out, int out_size, void* d_ws, size_t ws_size,
                              hipStream_t stream) {
    const float* nfeat = (const float*)d_in[0];
    const int*   mask  = (const int*)d_in[1];
    const float* ln1_g = (const float*)d_in[2];
    const float* ln1_b = (const float*)d_in[3];
    const float* bo    = (const float*)d_in[11];
    const float* ln2_g = (const float*)d_in[12];
    const float* ln2_b = (const float*)d_in[13];
    const float* fc1_b = (const float*)d_in[15];
    const float* fc2_b = (const float*)d_in[17];

    const size_t ND = (size_t)NN * DD;
    float* x    = (float*)d_ws;                      // 8 MB
    u16*   h    = (u16*)(x + ND);                    // 4 MB
    u16*   qkv  = h + ND;                            // 12 MB
    u16*   o    = qkv + (size_t)NN * 1536;           // 4 MB
    u16*   m1   = o + ND;                            // 4 MB
    u16*   wc   = m1 + ND;                           // 12 MB
    float* bcat = (float*)(wc + (size_t)12 * DD * DD);
    int*   idx  = (int*)(bcat + 2 * 1536);           // 4 MB
    int*   cnt  = idx + (size_t)NN * CAP;

    W6 w6;
    w6.w[0] = (const float*)d_in[4];  w6.w[1] = (const float*)d_in[6];
    w6.w[2] = (const float*)d_in[8];  w6.w[3] = (const float*)d_in[10];
    w6.w[4] = (const float*)d_in[14]; w6.w[5] = (const float*)d_in[16];
    w6.bq = (const float*)d_in[5]; w6.bk = (const float*)d_in[7]; w6.bv = (const float*)d_in[9];
    cast_weights<<<192, 256, 0, stream>>>(w6, wc, bcat);
    build_idx_kernel<<<NN, 256, 0, stream>>>(mask, idx, cnt);

    const size_t SS = (size_t)DD * DD;
    for (int l = 0; l < 2; l++) {
        size_t bOff = (size_t)l * DD;
        u16* wl = wc + (size_t)l * 6 * SS;
        const float* xin = (l == 0) ? nfeat : x;
        float* fc2_dst = (l == 1) ? (float*)d_out : x;

        ln_kernel<<<NN / 4, 256, 0, stream>>>(xin, ln1_g + bOff, ln1_b + bOff, h);
        gemm_qkv<<<dim3(24, 32), 256, 0, stream>>>(h, wl, bcat + l * 1536, qkv);
        sparse_attn<<<NN / 4, 512, 0, stream>>>(qkv, idx, cnt, o);
        gemm_bf16<2><<<dim3(8, 64), 256, 0, stream>>>(o, wl + 3 * SS, bo + bOff,
                                                      xin, x, nullptr, NN, DD, DD);
        ln_kernel<<<NN / 4, 256, 0, stream>>>(x, ln2_g + bOff, ln2_b + bOff, h);
        gemm_bf16<1><<<dim3(8, 64), 256, 0, stream>>>(h, wl + 4 * SS, fc1_b + bOff,
                                                      nullptr, nullptr, m1, NN, FF, DD);
        gemm_bf16<2><<<dim3(8, 64), 256, 0, stream>>>(m1, wl + 5 * SS, fc2_b + bOff,
                                                      x, fc2_dst, nullptr, NN, DD, FF);
    }
}

// Round 9
// 303.231 us; speedup vs baseline: 1.0397x; 1.0397x over previous
//
#include <hip/hip_runtime.h>
#include <math.h>

#define NN 4096
#define DD 512
#define FF 512
#define CAP 256
#define SCALE 0.08838834764831845f

typedef unsigned short u16;
typedef __attribute__((ext_vector_type(8))) short short8;
typedef __attribute__((ext_vector_type(8))) unsigned short ushort8;
typedef __attribute__((ext_vector_type(4))) unsigned short ushort4v;
typedef __attribute__((ext_vector_type(4))) float floatx4;

__device__ __forceinline__ float bf2f(u16 u) {
    union { unsigned int i; float f; } x; x.i = ((unsigned int)u) << 16; return x.f;
}
__device__ __forceinline__ u16 f2bf(float f) {
    union { float f; unsigned int i; } x; x.f = f;
    unsigned int r = (x.i + 0x7FFFu + ((x.i >> 16) & 1u)) >> 16;
    return (u16)r;
}
__device__ __forceinline__ void gld_lds16(const void* g, void* l) {
    __builtin_amdgcn_global_load_lds((const __attribute__((address_space(1))) void*)g,
                                     (__attribute__((address_space(3))) void*)l, 16, 0, 0);
}

// ---------------------------------------------------------------- mask -> idx (R3-proven)
__global__ void build_idx_kernel(const int* __restrict__ mask,
                                 int* __restrict__ idx, int* __restrict__ cnt) {
    int row = blockIdx.x;
    __shared__ int c;
    if (threadIdx.x == 0) c = 0;
    __syncthreads();
    const int4* mrow = (const int4*)(mask + (size_t)row * NN);
    for (int j4 = threadIdx.x; j4 < NN / 4; j4 += blockDim.x) {
        int4 m4 = mrow[j4];
        int base = j4 * 4;
        if (m4.x == 0) idx[row * CAP + atomicAdd(&c, 1)] = base;
        if (m4.y == 0) idx[row * CAP + atomicAdd(&c, 1)] = base + 1;
        if (m4.z == 0) idx[row * CAP + atomicAdd(&c, 1)] = base + 2;
        if (m4.w == 0) idx[row * CAP + atomicAdd(&c, 1)] = base + 3;
    }
    __syncthreads();
    if (threadIdx.x == 0) cnt[row] = (c < CAP) ? c : CAP;
}

// ---------------------------------------------------------------- weights fp32 -> bf16 (+ bias concat)
struct W6 {
    const float* w[6];
    const float* bq; const float* bk; const float* bv;
};
__global__ void cast_weights(W6 wp, u16* __restrict__ dst, float* __restrict__ bcat) {
    int region = blockIdx.x >> 4;
    int layer = region / 6, mat = region - layer * 6;
    const float* src = wp.w[mat] + (size_t)layer * (DD * DD);
    u16* d = dst + (size_t)region * (DD * DD);
    int off = (blockIdx.x & 15) * 16384 + threadIdx.x * 4;
#pragma unroll
    for (int i = 0; i < 16; i++) {
        int e = off + i * 1024;
        float4 f = *(const float4*)&src[e];
        ushort4v u;
        u.x = f2bf(f.x); u.y = f2bf(f.y); u.z = f2bf(f.z); u.w = f2bf(f.w);
        *(ushort4v*)&d[e] = u;
    }
    if (blockIdx.x < 2) {   // bias concat for layer = blockIdx.x
        int l = blockIdx.x;
        for (int it = 0; it < 6; it++) {
            int j = it * 256 + threadIdx.x;          // 0..1535
            int m = j >> 9, col = j & 511;
            const float* bp = (m == 0) ? wp.bq : (m == 1) ? wp.bk : wp.bv;
            bcat[l * 1536 + j] = bp[l * DD + col];
        }
    }
}

// ---------------------------------------------------------------- layernorm (fp32 in, bf16 out)
__global__ void ln_kernel(const float* __restrict__ x, const float* __restrict__ g,
                          const float* __restrict__ b, u16* __restrict__ out) {
    int wave = threadIdx.x >> 6, lane = threadIdx.x & 63;
    int row = blockIdx.x * 4 + wave;
    const float* xr = x + (size_t)row * DD;
    float4 p0 = *(const float4*)&xr[lane * 8];
    float4 p1 = *(const float4*)&xr[lane * 8 + 4];
    float v[8] = {p0.x, p0.y, p0.z, p0.w, p1.x, p1.y, p1.z, p1.w};
    float s = 0.f;
#pragma unroll
    for (int i = 0; i < 8; i++) s += v[i];
#pragma unroll
    for (int off = 32; off; off >>= 1) s += __shfl_xor(s, off);
    float mu = s * (1.0f / DD);
    float vs = 0.f;
#pragma unroll
    for (int i = 0; i < 8; i++) { float d = v[i] - mu; vs += d * d; }
#pragma unroll
    for (int off = 32; off; off >>= 1) vs += __shfl_xor(vs, off);
    float r = rsqrtf(vs * (1.0f / DD) + 1e-5f);
    float4 g0 = *(const float4*)&g[lane * 8];
    float4 g1 = *(const float4*)&g[lane * 8 + 4];
    float4 b0 = *(const float4*)&b[lane * 8];
    float4 b1 = *(const float4*)&b[lane * 8 + 4];
    float ge[8] = {g0.x, g0.y, g0.z, g0.w, g1.x, g1.y, g1.z, g1.w};
    float be[8] = {b0.x, b0.y, b0.z, b0.w, b1.x, b1.y, b1.z, b1.w};
    ushort8 ov;
#pragma unroll
    for (int i = 0; i < 8; i++) ov[i] = f2bf((v[i] - mu) * r * ge[i] + be[i]);
    *(ushort8*)&out[(size_t)row * DD + lane * 8] = ov;
}

// ---------------------------------------------------------------- 64x64 GEMM (R3-proven)
// MODE 0: -> bf16; 1: gelu -> bf16; 2: resOut = resIn + val (fp32)
template <int MODE>
__launch_bounds__(256)
__global__ void gemm_bf16(const u16* __restrict__ A, const u16* __restrict__ B,
                          const float* __restrict__ bias, const float* __restrict__ resIn,
                          float* __restrict__ resOut, u16* __restrict__ outB,
                          int M, int Nout, int K) {
    __shared__ u16 As[64 * 32];
    __shared__ u16 Bs[64 * 32];
    const int m0 = blockIdx.y * 64, n0 = blockIdx.x * 64;
    const int t = threadIdx.x;
    const int wave = t >> 6, lane = t & 63;
    const int wm = (wave & 1) * 32, wn = (wave >> 1) * 32;
    const int srow = t >> 2, scol = (t & 3) * 8;
    const int fr = lane & 15, fq = (lane >> 4) * 8;

    floatx4 acc[2][2] = {};
    const u16* ag = A + (size_t)(m0 + srow) * K + scol;
    const u16* bg = B + (size_t)(n0 + srow) * K + scol;
    u16* as = As + t * 8;
    u16* bs = Bs + t * 8;

    for (int k0 = 0; k0 < K; k0 += 32) {
        __syncthreads();
        gld_lds16(ag + k0, as);
        gld_lds16(bg + k0, bs);
        __syncthreads();
        short8 af[2], bf[2];
#pragma unroll
        for (int i = 0; i < 2; i++) af[i] = *(const short8*)&As[(wm + 16 * i + fr) * 32 + fq];
#pragma unroll
        for (int j = 0; j < 2; j++) bf[j] = *(const short8*)&Bs[(wn + 16 * j + fr) * 32 + fq];
#pragma unroll
        for (int i = 0; i < 2; i++)
#pragma unroll
            for (int j = 0; j < 2; j++)
                acc[i][j] = __builtin_amdgcn_mfma_f32_16x16x32_bf16(af[i], bf[j], acc[i][j], 0, 0, 0);
    }

    const int er = (lane >> 4) * 4, ec = lane & 15;
#pragma unroll
    for (int i = 0; i < 2; i++) {
#pragma unroll
        for (int j = 0; j < 2; j++) {
            int col = n0 + wn + 16 * j + ec;
            float bsv = bias[col];
#pragma unroll
            for (int r = 0; r < 4; r++) {
                int row = m0 + wm + 16 * i + er + r;
                float val = acc[i][j][r] + bsv;
                if (MODE == 1) val = 0.5f * val * (1.0f + erff(val * 0.70710678118654752f));
                if (MODE == 2) {
                    resOut[(size_t)row * Nout + col] = resIn[(size_t)row * Nout + col] + val;
                } else {
                    outB[(size_t)row * Nout + col] = f2bf(val);
                }
            }
        }
    }
}

// ---------------------------------------------------------------- 128x64 QKV GEMM (R7-proven)
__launch_bounds__(256)
__global__ void gemm_qkv(const u16* __restrict__ A, const u16* __restrict__ B,
                         const float* __restrict__ bias, u16* __restrict__ outB) {
    __shared__ u16 As[128 * 32];
    __shared__ u16 Bs[64 * 32];
    const int m0 = blockIdx.y * 128, n0 = blockIdx.x * 64;
    const int t = threadIdx.x;
    const int wave = t >> 6, lane = t & 63;
    const int wm = (wave & 1) * 64, wn = (wave >> 1) * 32;
    const int srow = t >> 2, scol = (t & 3) * 8;
    const int fr = lane & 15, fq = (lane >> 4) * 8;

    floatx4 acc[4][2] = {};
    const u16* ag0 = A + (size_t)(m0 + srow) * DD + scol;
    const u16* ag1 = ag0 + (size_t)64 * DD;
    const u16* bg = B + (size_t)(n0 + srow) * DD + scol;
    u16* as0 = As + t * 8;
    u16* as1 = as0 + 64 * 32;
    u16* bs = Bs + t * 8;

    for (int k0 = 0; k0 < DD; k0 += 32) {
        __syncthreads();
        gld_lds16(ag0 + k0, as0);
        gld_lds16(ag1 + k0, as1);
        gld_lds16(bg + k0, bs);
        __syncthreads();
        short8 af[4], bf[2];
#pragma unroll
        for (int i = 0; i < 4; i++) af[i] = *(const short8*)&As[(wm + 16 * i + fr) * 32 + fq];
#pragma unroll
        for (int j = 0; j < 2; j++) bf[j] = *(const short8*)&Bs[(wn + 16 * j + fr) * 32 + fq];
#pragma unroll
        for (int i = 0; i < 4; i++)
#pragma unroll
            for (int j = 0; j < 2; j++)
                acc[i][j] = __builtin_amdgcn_mfma_f32_16x16x32_bf16(af[i], bf[j], acc[i][j], 0, 0, 0);
    }

    const int er = (lane >> 4) * 4, ec = lane & 15;
#pragma unroll
    for (int j = 0; j < 2; j++) {
        int col = n0 + wn + 16 * j + ec;
        float bsv = bias[col];
#pragma unroll
        for (int i = 0; i < 4; i++) {
#pragma unroll
            for (int r = 0; r < 4; r++) {
                int row = m0 + wm + 16 * i + er + r;
                outB[(size_t)row * 1536 + col] = f2bf(acc[i][j][r] + bsv);
            }
        }
    }
}

// ---------------------------------------------------------------- sparse attention
// 4 waves/query (key-split x4), 2 queries/block (512 thr); idx in LDS; next-key prefetch
__global__ void sparse_attn(const u16* __restrict__ qkv, const int* __restrict__ idx,
                            const int* __restrict__ cnt, u16* __restrict__ o) {
    int t = threadIdx.x;
    int wave = t >> 6, lane = t & 63;
    int qslot = wave >> 2, quarter = wave & 3;
    int qi = blockIdx.x * 2 + qslot;
    __shared__ float obuf[2][3][64][8];
    __shared__ float sbuf[2][3][64];
    __shared__ int sidx[2][CAP];

    int c = cnt[qi];
    const int* ir = idx + qi * CAP;
    for (int j = t & 255; j < c; j += 256) sidx[qslot][j] = ir[j];

    ushort8 qv = *(const ushort8*)(qkv + (size_t)qi * 1536 + lane * 8);
    float qf[8];
#pragma unroll
    for (int e = 0; e < 8; e++) qf[e] = bf2f(qv[e]);
    __syncthreads();

    float sum = 0.f, oa[8] = {};
    int j = quarter;
    ushort8 kv, vv;
    if (j < c) {
        const u16* kb = qkv + (size_t)sidx[qslot][j] * 1536;
        kv = *(const ushort8*)(kb + 512 + lane * 8);
        vv = *(const ushort8*)(kb + 1024 + lane * 8);
    }
    while (j < c) {
        int jn = j + 4;
        ushort8 kvn, vvn;
        {   // prefetch next key in this wave's stream
            int kjn = (jn < c) ? sidx[qslot][jn] : 0;
            const u16* nb = qkv + (size_t)kjn * 1536;
            kvn = *(const ushort8*)(nb + 512 + lane * 8);
            vvn = *(const ushort8*)(nb + 1024 + lane * 8);
        }
        float d = 0.f;
#pragma unroll
        for (int e = 0; e < 8; e++) d += qf[e] * bf2f(kv[e]);
        d += __shfl_xor(d, 1);
        d += __shfl_xor(d, 2);
        d += __shfl_xor(d, 4);
        d += __shfl_xor(d, 8);
        float p = __expf(d * SCALE);
        sum += p;
#pragma unroll
        for (int e = 0; e < 8; e++) oa[e] += p * bf2f(vv[e]);
        kv = kvn; vv = vvn;
        j = jn;
    }

    if (quarter != 0) {
#pragma unroll
        for (int e = 0; e < 8; e++) obuf[qslot][quarter - 1][lane][e] = oa[e];
        sbuf[qslot][quarter - 1][lane] = sum;
    }
    __syncthreads();
    if (quarter == 0) {
#pragma unroll
        for (int u = 0; u < 3; u++) {
            sum += sbuf[qslot][u][lane];
#pragma unroll
            for (int e = 0; e < 8; e++) oa[e] += obuf[qslot][u][lane][e];
        }
        float inv = 1.0f / sum;
        ushort8 ov;
#pragma unroll
        for (int e = 0; e < 8; e++) ov[e] = f2bf(oa[e] * inv);
        *(ushort8*)(o + (size_t)qi * 512 + lane * 8) = ov;
    }
}

// ---------------------------------------------------------------- launch
extern "C" void kernel_launch(void* const* d_in, const int* in_sizes, int n_in,
                              void* d_out, int out_size, void* d_ws, size_t ws_size,
                              hipStream_t stream) {
    const float* nfeat = (const float*)d_in[0];
    const int*   mask  = (const int*)d_in[1];
    const float* ln1_g = (const float*)d_in[2];
    const float* ln1_b = (const float*)d_in[3];
    const float* bo    = (const float*)d_in[11];
    const float* ln2_g = (const float*)d_in[12];
    const float* ln2_b = (const float*)d_in[13];
    const float* fc1_b = (const float*)d_in[15];
    const float* fc2_b = (const float*)d_in[17];

    const size_t ND = (size_t)NN * DD;
    float* x    = (float*)d_ws;                      // 8 MB
    u16*   h    = (u16*)(x + ND);                    // 4 MB
    u16*   qkv  = h + ND;                            // 12 MB
    u16*   o    = qkv + (size_t)NN * 1536;           // 4 MB
    u16*   m1   = o + ND;                            // 4 MB
    u16*   wc   = m1 + ND;                           // 12 MB
    float* bcat = (float*)(wc + (size_t)12 * DD * DD);
    int*   idx  = (int*)(bcat + 2 * 1536);           // 4 MB
    int*   cnt  = idx + (size_t)NN * CAP;

    W6 w6;
    w6.w[0] = (const float*)d_in[4];  w6.w[1] = (const float*)d_in[6];
    w6.w[2] = (const float*)d_in[8];  w6.w[3] = (const float*)d_in[10];
    w6.w[4] = (const float*)d_in[14]; w6.w[5] = (const float*)d_in[16];
    w6.bq = (const float*)d_in[5]; w6.bk = (const float*)d_in[7]; w6.bv = (const float*)d_in[9];
    cast_weights<<<192, 256, 0, stream>>>(w6, wc, bcat);
    build_idx_kernel<<<NN, 256, 0, stream>>>(mask, idx, cnt);

    const size_t SS = (size_t)DD * DD;
    for (int l = 0; l < 2; l++) {
        size_t bOff = (size_t)l * DD;
        u16* wl = wc + (size_t)l * 6 * SS;
        const float* xin = (l == 0) ? nfeat : x;
        float* fc2_dst = (l == 1) ? (float*)d_out : x;

        ln_kernel<<<NN / 4, 256, 0, stream>>>(xin, ln1_g + bOff, ln1_b + bOff, h);
        gemm_qkv<<<dim3(24, 32), 256, 0, stream>>>(h, wl, bcat + l * 1536, qkv);
        sparse_attn<<<NN / 2, 512, 0, stream>>>(qkv, idx, cnt, o);
        gemm_bf16<2><<<dim3(8, 64), 256, 0, stream>>>(o, wl + 3 * SS, bo + bOff,
                                                      xin, x, nullptr, NN, DD, DD);
        ln_kernel<<<NN / 4, 256, 0, stream>>>(x, ln2_g + bOff, ln2_b + bOff, h);
        gemm_bf16<1><<<dim3(8, 64), 256, 0, stream>>>(h, wl + 4 * SS, fc1_b + bOff,
                                                      nullptr, nullptr, m1, NN, FF, DD);
        gemm_bf16<2><<<dim3(8, 64), 256, 0, stream>>>(m1, wl + 5 * SS, fc2_b + bOff,
                                                      x, fc2_dst, nullptr, NN, DD, FF);
    }
}

// Round 10
// 288.724 us; speedup vs baseline: 1.0919x; 1.0502x over previous
//
#include <hip/hip_runtime.h>
#include <math.h>

#define NN 4096
#define DD 512
#define FF 512
#define CAP 256
#define SCALE 0.08838834764831845f

typedef unsigned short u16;
typedef __attribute__((ext_vector_type(8))) short short8;
typedef __attribute__((ext_vector_type(8))) unsigned short ushort8;
typedef __attribute__((ext_vector_type(4))) unsigned short ushort4v;
typedef __attribute__((ext_vector_type(4))) float floatx4;

__device__ __forceinline__ float bf2f(u16 u) {
    union { unsigned int i; float f; } x; x.i = ((unsigned int)u) << 16; return x.f;
}
__device__ __forceinline__ u16 f2bf(float f) {
    union { float f; unsigned int i; } x; x.f = f;
    unsigned int r = (x.i + 0x7FFFu + ((x.i >> 16) & 1u)) >> 16;
    return (u16)r;
}
__device__ __forceinline__ void gld_lds16(const void* g, void* l) {
    __builtin_amdgcn_global_load_lds((const __attribute__((address_space(1))) void*)g,
                                     (__attribute__((address_space(3))) void*)l, 16, 0, 0);
}

// ---------------------------------------------------------------- mask -> idx (R3-proven)
__global__ void build_idx_kernel(const int* __restrict__ mask,
                                 int* __restrict__ idx, int* __restrict__ cnt) {
    int row = blockIdx.x;
    __shared__ int c;
    if (threadIdx.x == 0) c = 0;
    __syncthreads();
    const int4* mrow = (const int4*)(mask + (size_t)row * NN);
    for (int j4 = threadIdx.x; j4 < NN / 4; j4 += blockDim.x) {
        int4 m4 = mrow[j4];
        int base = j4 * 4;
        if (m4.x == 0) idx[row * CAP + atomicAdd(&c, 1)] = base;
        if (m4.y == 0) idx[row * CAP + atomicAdd(&c, 1)] = base + 1;
        if (m4.z == 0) idx[row * CAP + atomicAdd(&c, 1)] = base + 2;
        if (m4.w == 0) idx[row * CAP + atomicAdd(&c, 1)] = base + 3;
    }
    __syncthreads();
    if (threadIdx.x == 0) cnt[row] = (c < CAP) ? c : CAP;
}

// ---------------------------------------------------------------- weights fp32 -> bf16 (+ bias concat)
struct W6 {
    const float* w[6];
    const float* bq; const float* bk; const float* bv;
};
__global__ void cast_weights(W6 wp, u16* __restrict__ dst, float* __restrict__ bcat) {
    int region = blockIdx.x >> 4;
    int layer = region / 6, mat = region - layer * 6;
    const float* src = wp.w[mat] + (size_t)layer * (DD * DD);
    u16* d = dst + (size_t)region * (DD * DD);
    int off = (blockIdx.x & 15) * 16384 + threadIdx.x * 4;
#pragma unroll
    for (int i = 0; i < 16; i++) {
        int e = off + i * 1024;
        float4 f = *(const float4*)&src[e];
        ushort4v u;
        u.x = f2bf(f.x); u.y = f2bf(f.y); u.z = f2bf(f.z); u.w = f2bf(f.w);
        *(ushort4v*)&d[e] = u;
    }
    if (blockIdx.x < 2) {   // bias concat for layer = blockIdx.x
        int l = blockIdx.x;
        for (int it = 0; it < 6; it++) {
            int j = it * 256 + threadIdx.x;          // 0..1535
            int m = j >> 9, col = j & 511;
            const float* bp = (m == 0) ? wp.bq : (m == 1) ? wp.bk : wp.bv;
            bcat[l * 1536 + j] = bp[l * DD + col];
        }
    }
}

// ---------------------------------------------------------------- layernorm (fp32 in, bf16 out)
__global__ void ln_kernel(const float* __restrict__ x, const float* __restrict__ g,
                          const float* __restrict__ b, u16* __restrict__ out) {
    int wave = threadIdx.x >> 6, lane = threadIdx.x & 63;
    int row = blockIdx.x * 4 + wave;
    const float* xr = x + (size_t)row * DD;
    float4 p0 = *(const float4*)&xr[lane * 8];
    float4 p1 = *(const float4*)&xr[lane * 8 + 4];
    float v[8] = {p0.x, p0.y, p0.z, p0.w, p1.x, p1.y, p1.z, p1.w};
    float s = 0.f;
#pragma unroll
    for (int i = 0; i < 8; i++) s += v[i];
#pragma unroll
    for (int off = 32; off; off >>= 1) s += __shfl_xor(s, off);
    float mu = s * (1.0f / DD);
    float vs = 0.f;
#pragma unroll
    for (int i = 0; i < 8; i++) { float d = v[i] - mu; vs += d * d; }
#pragma unroll
    for (int off = 32; off; off >>= 1) vs += __shfl_xor(vs, off);
    float r = rsqrtf(vs * (1.0f / DD) + 1e-5f);
    float4 g0 = *(const float4*)&g[lane * 8];
    float4 g1 = *(const float4*)&g[lane * 8 + 4];
    float4 b0 = *(const float4*)&b[lane * 8];
    float4 b1 = *(const float4*)&b[lane * 8 + 4];
    float ge[8] = {g0.x, g0.y, g0.z, g0.w, g1.x, g1.y, g1.z, g1.w};
    float be[8] = {b0.x, b0.y, b0.z, b0.w, b1.x, b1.y, b1.z, b1.w};
    ushort8 ov;
#pragma unroll
    for (int i = 0; i < 8; i++) ov[i] = f2bf((v[i] - mu) * r * ge[i] + be[i]);
    *(ushort8*)&out[(size_t)row * DD + lane * 8] = ov;
}

// ---------------------------------------------------------------- 64x64 GEMM, BK=64
// LDS row-major 64 cols; staging: thread t -> rows (t>>3, 32+(t>>3)), chunk t&7.
// Wave-contiguous LDS dest: base + lane*16 for each 32-row group.
// MODE 0: -> bf16; 1: gelu -> bf16; 2: resOut = resIn + val (fp32)
template <int MODE>
__launch_bounds__(256)
__global__ void gemm_bf16(const u16* __restrict__ A, const u16* __restrict__ B,
                          const float* __restrict__ bias, const float* __restrict__ resIn,
                          float* __restrict__ resOut, u16* __restrict__ outB,
                          int M, int Nout, int K) {
    __shared__ u16 As[64 * 64];
    __shared__ u16 Bs[64 * 64];
    const int m0 = blockIdx.y * 64, n0 = blockIdx.x * 64;
    const int t = threadIdx.x;
    const int wave = t >> 6, lane = t & 63;
    const int wm = (wave & 1) * 32, wn = (wave >> 1) * 32;
    const int sr = t >> 3, sc = (t & 7) * 8;
    const int fr = lane & 15, fq = (lane >> 4) * 8;

    floatx4 acc[2][2] = {};
    const u16* ag0 = A + (size_t)(m0 + sr) * K + sc;
    const u16* ag1 = A + (size_t)(m0 + 32 + sr) * K + sc;
    const u16* bg0 = B + (size_t)(n0 + sr) * K + sc;
    const u16* bg1 = B + (size_t)(n0 + 32 + sr) * K + sc;
    u16* as0 = As + t * 8;
    u16* as1 = As + 32 * 64 + t * 8;
    u16* bs0 = Bs + t * 8;
    u16* bs1 = Bs + 32 * 64 + t * 8;

    for (int k0 = 0; k0 < K; k0 += 64) {
        __syncthreads();
        gld_lds16(ag0 + k0, as0);
        gld_lds16(ag1 + k0, as1);
        gld_lds16(bg0 + k0, bs0);
        gld_lds16(bg1 + k0, bs1);
        __syncthreads();
#pragma unroll
        for (int h = 0; h < 2; h++) {
            short8 af[2], bf[2];
#pragma unroll
            for (int i = 0; i < 2; i++) af[i] = *(const short8*)&As[(wm + 16 * i + fr) * 64 + h * 32 + fq];
#pragma unroll
            for (int j = 0; j < 2; j++) bf[j] = *(const short8*)&Bs[(wn + 16 * j + fr) * 64 + h * 32 + fq];
#pragma unroll
            for (int i = 0; i < 2; i++)
#pragma unroll
                for (int j = 0; j < 2; j++)
                    acc[i][j] = __builtin_amdgcn_mfma_f32_16x16x32_bf16(af[i], bf[j], acc[i][j], 0, 0, 0);
        }
    }

    const int er = (lane >> 4) * 4, ec = lane & 15;
#pragma unroll
    for (int i = 0; i < 2; i++) {
#pragma unroll
        for (int j = 0; j < 2; j++) {
            int col = n0 + wn + 16 * j + ec;
            float bsv = bias[col];
#pragma unroll
            for (int r = 0; r < 4; r++) {
                int row = m0 + wm + 16 * i + er + r;
                float val = acc[i][j][r] + bsv;
                if (MODE == 1) val = 0.5f * val * (1.0f + erff(val * 0.70710678118654752f));
                if (MODE == 2) {
                    resOut[(size_t)row * Nout + col] = resIn[(size_t)row * Nout + col] + val;
                } else {
                    outB[(size_t)row * Nout + col] = f2bf(val);
                }
            }
        }
    }
}

// ---------------------------------------------------------------- 128x64 QKV GEMM, BK=64
__launch_bounds__(256)
__global__ void gemm_qkv(const u16* __restrict__ A, const u16* __restrict__ B,
                         const float* __restrict__ bias, u16* __restrict__ outB) {
    __shared__ u16 As[128 * 64];   // 16 KB
    __shared__ u16 Bs[64 * 64];    // 8 KB
    const int m0 = blockIdx.y * 128, n0 = blockIdx.x * 64;
    const int t = threadIdx.x;
    const int wave = t >> 6, lane = t & 63;
    const int wm = (wave & 1) * 64, wn = (wave >> 1) * 32;
    const int sr = t >> 3, sc = (t & 7) * 8;
    const int fr = lane & 15, fq = (lane >> 4) * 8;

    floatx4 acc[4][2] = {};
    const u16* agp[4];
    u16* asp[4];
#pragma unroll
    for (int u = 0; u < 4; u++) {
        agp[u] = A + (size_t)(m0 + 32 * u + sr) * DD + sc;
        asp[u] = As + u * (32 * 64) + t * 8;
    }
    const u16* bg0 = B + (size_t)(n0 + sr) * DD + sc;
    const u16* bg1 = B + (size_t)(n0 + 32 + sr) * DD + sc;
    u16* bs0 = Bs + t * 8;
    u16* bs1 = Bs + 32 * 64 + t * 8;

    for (int k0 = 0; k0 < DD; k0 += 64) {
        __syncthreads();
#pragma unroll
        for (int u = 0; u < 4; u++) gld_lds16(agp[u] + k0, asp[u]);
        gld_lds16(bg0 + k0, bs0);
        gld_lds16(bg1 + k0, bs1);
        __syncthreads();
#pragma unroll
        for (int h = 0; h < 2; h++) {
            short8 af[4], bf[2];
#pragma unroll
            for (int i = 0; i < 4; i++) af[i] = *(const short8*)&As[(wm + 16 * i + fr) * 64 + h * 32 + fq];
#pragma unroll
            for (int j = 0; j < 2; j++) bf[j] = *(const short8*)&Bs[(wn + 16 * j + fr) * 64 + h * 32 + fq];
#pragma unroll
            for (int i = 0; i < 4; i++)
#pragma unroll
                for (int j = 0; j < 2; j++)
                    acc[i][j] = __builtin_amdgcn_mfma_f32_16x16x32_bf16(af[i], bf[j], acc[i][j], 0, 0, 0);
        }
    }

    const int er = (lane >> 4) * 4, ec = lane & 15;
#pragma unroll
    for (int j = 0; j < 2; j++) {
        int col = n0 + wn + 16 * j + ec;
        float bsv = bias[col];
#pragma unroll
        for (int i = 0; i < 4; i++) {
#pragma unroll
            for (int r = 0; r < 4; r++) {
                int row = m0 + wm + 16 * i + er + r;
                outB[(size_t)row * 1536 + col] = f2bf(acc[i][j][r] + bsv);
            }
        }
    }
}

// ---------------------------------------------------------------- sparse attention (R7-proven)
// 2 waves/query, 4 queries/block; idx list in LDS; 2-deep K/V load pipeline
__global__ void sparse_attn(const u16* __restrict__ qkv, const int* __restrict__ idx,
                            const int* __restrict__ cnt, u16* __restrict__ o) {
    int t = threadIdx.x;
    int wave = t >> 6, lane = t & 63;
    int qslot = wave >> 1, half = wave & 1;
    int qi = blockIdx.x * 4 + qslot;
    __shared__ float obuf[4][64][8];
    __shared__ float sbuf[4][64];
    __shared__ int sidx[4][CAP];

    int c = cnt[qi];
    const int* ir = idx + qi * CAP;
    for (int j = t & 127; j < c; j += 128) sidx[qslot][j] = ir[j];

    ushort8 qv = *(const ushort8*)(qkv + (size_t)qi * 1536 + lane * 8);
    float qf[8];
#pragma unroll
    for (int e = 0; e < 8; e++) qf[e] = bf2f(qv[e]);
    __syncthreads();

    float sum = 0.f, oa[8] = {};
    int j = half;
    ushort8 kv, vv;
    if (j < c) {
        const u16* kb = qkv + (size_t)sidx[qslot][j] * 1536;
        kv = *(const ushort8*)(kb + 512 + lane * 8);
        vv = *(const ushort8*)(kb + 1024 + lane * 8);
    }
    while (j < c) {
        int jn = j + 2;
        ushort8 kvn, vvn;
        {
            int kjn = (jn < c) ? sidx[qslot][jn] : 0;
            const u16* nb = qkv + (size_t)kjn * 1536;
            kvn = *(const ushort8*)(nb + 512 + lane * 8);
            vvn = *(const ushort8*)(nb + 1024 + lane * 8);
        }
        float d = 0.f;
#pragma unroll
        for (int e = 0; e < 8; e++) d += qf[e] * bf2f(kv[e]);
        d += __shfl_xor(d, 1);
        d += __shfl_xor(d, 2);
        d += __shfl_xor(d, 4);
        d += __shfl_xor(d, 8);
        float p = __expf(d * SCALE);
        sum += p;
#pragma unroll
        for (int e = 0; e < 8; e++) oa[e] += p * bf2f(vv[e]);
        kv = kvn; vv = vvn;
        j = jn;
    }

    if (half == 1) {
#pragma unroll
        for (int e = 0; e < 8; e++) obuf[qslot][lane][e] = oa[e];
        sbuf[qslot][lane] = sum;
    }
    __syncthreads();
    if (half == 0) {
        sum += sbuf[qslot][lane];
        float inv = 1.0f / sum;
        ushort8 ov;
#pragma unroll
        for (int e = 0; e < 8; e++) ov[e] = f2bf((oa[e] + obuf[qslot][lane][e]) * inv);
        *(ushort8*)(o + (size_t)qi * 512 + lane * 8) = ov;
    }
}

// ---------------------------------------------------------------- launch
extern "C" void kernel_launch(void* const* d_in, const int* in_sizes, int n_in,
                              void* d_out, int out_size, void* d_ws, size_t ws_size,
                              hipStream_t stream) {
    const float* nfeat = (const float*)d_in[0];
    const int*   mask  = (const int*)d_in[1];
    const float* ln1_g = (const float*)d_in[2];
    const float* ln1_b = (const float*)d_in[3];
    const float* bo    = (const float*)d_in[11];
    const float* ln2_g = (const float*)d_in[12];
    const float* ln2_b = (const float*)d_in[13];
    const float* fc1_b = (const float*)d_in[15];
    const float* fc2_b = (const float*)d_in[17];

    const size_t ND = (size_t)NN * DD;
    float* x    = (float*)d_ws;                      // 8 MB
    u16*   h    = (u16*)(x + ND);                    // 4 MB
    u16*   qkv  = h + ND;                            // 12 MB
    u16*   o    = qkv + (size_t)NN * 1536;           // 4 MB
    u16*   m1   = o + ND;                            // 4 MB
    u16*   wc   = m1 + ND;                           // 12 MB
    float* bcat = (float*)(wc + (size_t)12 * DD * DD);
    int*   idx  = (int*)(bcat + 2 * 1536);           // 4 MB
    int*   cnt  = idx + (size_t)NN * CAP;

    W6 w6;
    w6.w[0] = (const float*)d_in[4];  w6.w[1] = (const float*)d_in[6];
    w6.w[2] = (const float*)d_in[8];  w6.w[3] = (const float*)d_in[10];
    w6.w[4] = (const float*)d_in[14]; w6.w[5] = (const float*)d_in[16];
    w6.bq = (const float*)d_in[5]; w6.bk = (const float*)d_in[7]; w6.bv = (const float*)d_in[9];
    cast_weights<<<192, 256, 0, stream>>>(w6, wc, bcat);
    build_idx_kernel<<<NN, 256, 0, stream>>>(mask, idx, cnt);

    const size_t SS = (size_t)DD * DD;
    for (int l = 0; l < 2; l++) {
        size_t bOff = (size_t)l * DD;
        u16* wl = wc + (size_t)l * 6 * SS;
        const float* xin = (l == 0) ? nfeat : x;
        float* fc2_dst = (l == 1) ? (float*)d_out : x;

        ln_kernel<<<NN / 4, 256, 0, stream>>>(xin, ln1_g + bOff, ln1_b + bOff, h);
        gemm_qkv<<<dim3(24, 32), 256, 0, stream>>>(h, wl, bcat + l * 1536, qkv);
        sparse_attn<<<NN / 4, 512, 0, stream>>>(qkv, idx, cnt, o);
        gemm_bf16<2><<<dim3(8, 64), 256, 0, stream>>>(o, wl + 3 * SS, bo + bOff,
                                                      xin, x, nullptr, NN, DD, DD);
        ln_kernel<<<NN / 4, 256, 0, stream>>>(x, ln2_g + bOff, ln2_b + bOff, h);
        gemm_bf16<1><<<dim3(8, 64), 256, 0, stream>>>(h, wl + 4 * SS, fc1_b + bOff,
                                                      nullptr, nullptr, m1, NN, FF, DD);
        gemm_bf16<2><<<dim3(8, 64), 256, 0, stream>>>(m1, wl + 5 * SS, fc2_b + bOff,
                                                      x, fc2_dst, nullptr, NN, DD, FF);
    }
}